// Round 5
// baseline (577.244 us; speedup 1.0000x reference)
//
#include <hip/hip_runtime.h>

#define T_LEN  16384
#define LTAG   64
#define F_PER  14
#define NCHUNK 256
#define CHUNK  64
#define BOS_ID 0
#define EOS_ID 1
#define NREG   10
#define REGSZ  500000      // 10 x 500000 = 5,000,000 = NB_FEATURES ; 2 MB per region

typedef __attribute__((ext_vector_type(4))) float f4;

// workspace layout (bytes)
static constexpr size_t EM_OFF = 0;                                  // float[T*64]  4 MB
static constexpr size_t P_OFF  = EM_OFF + (size_t)T_LEN * 64 * 4;    // float[256*4096] 4 MB
static constexpr size_t AB_OFF = P_OFF + (size_t)NCHUNK * 4096 * 4;  // double[257*64]
static constexpr size_t BP_OFF = AB_OFF + (size_t)257 * 64 * 8;      // uchar[T*64] 1 MB
static constexpr size_t G_OFF  = BP_OFF + (size_t)T_LEN * 64;        // uchar[256*64]
static constexpr size_t BT_OFF = G_OFF + (size_t)NCHUNK * 64;        // int[257]

// ---------------------------------------------------------------------------
// K1: emissions  em[t,l] = sum_f w[feat[t,l,f]]  (fp32)
// Region-sweep gather: idx held in registers (nontemporal load), table swept
// in 2 MB regions so co-resident blocks keep the active region hot in each
// XCD's L2 instead of thrashing 20 MB through 4 MB.
// ---------------------------------------------------------------------------
__global__ __launch_bounds__(256) void k_emissions(
    const int* __restrict__ idx, const float* __restrict__ w, float* __restrict__ em)
{
    const int tid = blockIdx.x * 256 + threadIdx.x;
    const int* p = idx + (size_t)tid * F_PER;
    int id[F_PER];
#pragma unroll
    for (int f = 0; f < F_PER; ++f) id[f] = __builtin_nontemporal_load(p + f);
    float s = 0.f;
    for (int r = 0; r < NREG; ++r) {
        const int lo = r * REGSZ;
        const int hi = lo + REGSZ;
#pragma unroll
        for (int f = 0; f < F_PER; ++f)
            if (id[f] >= lo && id[f] < hi) s += w[id[f]];
    }
    em[tid] = s;
}

// ---------------------------------------------------------------------------
// K2: phase 1 — per-chunk (max,+) transfer matrices, fp32, column-split,
// with max-plus rank-1 collapse early-exit.
// ---------------------------------------------------------------------------
__global__ __launch_bounds__(64) void k_phase1(
    const float* __restrict__ trans, const float* __restrict__ em, float* __restrict__ Pg)
{
    __shared__ float sT[4096];      // 16 KB  sT[k*64+j] = T[k][j]
    __shared__ float sP[64 * 16];   // 4 KB   sP[j*16+i] = P[j][ib+i]
    __shared__ float sEm[64 * 64];  // 16 KB  emissions for this chunk
    __shared__ float su[64];
    __shared__ float sv[16];
    __shared__ float spart[256];
    const int bb  = blockIdx.x;
    const int c   = bb >> 2;
    const int ib  = (bb & 3) << 4;
    const int tid = threadIdx.x;
    const int i0  = (tid & 3) << 2;
    const int j0  = (tid >> 2) << 2;
    const int t0  = c << 6;
    int nsteps = (T_LEN - 1) - t0; if (nsteps > CHUNK) nsteps = CHUNK;
    for (int x = tid; x < 4096; x += 64) sT[x] = trans[x];
    {   // stage emissions em[t0+1 .. t0+nsteps][:] -> sEm[s*64+j]
        const float* eg = em + (size_t)(t0 + 1) * 64;
        for (int x = tid * 4; x < nsteps * 64; x += 256)
            *(f4*)(sEm + x) = *(const f4*)(eg + x);
    }
    __syncthreads();

    float acc[4][4];
    // init step s=0: P[j][i] = e0[j] + T[ib+i][j]
    {
        const f4 e = *(const f4*)(sEm + j0);
#pragma unroll
        for (int jj = 0; jj < 4; ++jj) {
#pragma unroll
            for (int ii = 0; ii < 4; ++ii)
                acc[jj][ii] = e[jj] + sT[(ib + i0 + ii) * 64 + (j0 + jj)];
            f4 row = { acc[jj][0], acc[jj][1], acc[jj][2], acc[jj][3] };
            *(f4*)(sP + (j0 + jj) * 16 + i0) = row;
        }
    }
    __syncthreads();

    int coll = -1;
    for (int s = 1; s < nsteps; ++s) {
        const f4 e = *(const f4*)(sEm + s * 64 + j0);
#pragma unroll
        for (int jj = 0; jj < 4; ++jj)
#pragma unroll
            for (int ii = 0; ii < 4; ++ii) acc[jj][ii] = -3.0e38f;
#pragma unroll 8
        for (int k = 0; k < 64; k += 2) {
            const f4 ta = *(const f4*)(sT + k * 64 + j0);
            const f4 tb = *(const f4*)(sT + (k + 1) * 64 + j0);
            const f4 pa = *(const f4*)(sP + k * 16 + i0);
            const f4 pb = *(const f4*)(sP + (k + 1) * 16 + i0);
#pragma unroll
            for (int jj = 0; jj < 4; ++jj)
#pragma unroll
                for (int ii = 0; ii < 4; ++ii)
                    acc[jj][ii] = fmaxf(fmaxf(acc[jj][ii], ta[jj] + pa[ii]),
                                        tb[jj] + pb[ii]);
        }
        __syncthreads();
#pragma unroll
        for (int jj = 0; jj < 4; ++jj) {
            f4 row = { acc[jj][0] + e[jj], acc[jj][1] + e[jj],
                       acc[jj][2] + e[jj], acc[jj][3] + e[jj] };
            *(f4*)(sP + (j0 + jj) * 16 + i0) = row;
        }
        __syncthreads();
        // rank-1 check: (P[j][i]-P[j][0]) must equal (P[0][i]-P[0][0]) for all i,j
        {
            const f4 refi = *(const f4*)(sP + i0);   // row j=0, this thread's cols
            const float ref0 = sP[0];
            float dev = 0.f;
#pragma unroll
            for (int jj = 0; jj < 4; ++jj) {
                const float cj = sP[(j0 + jj) * 16];
#pragma unroll
                for (int ii = 0; ii < 4; ++ii) {
                    const float val = acc[jj][ii] + e[jj];
                    dev = fmaxf(dev, fabsf((val - cj) - (refi[ii] - ref0)));
                }
            }
            if (__ballot(dev <= 1.0e-2f) == ~0ULL) { coll = s; break; }
        }
    }

    if (coll >= 0) {
        // P = u + v ; run cheap vector recursion on u for remaining steps
        if (tid < 16) sv[tid] = sP[tid] - sP[0];
        su[tid] = sP[tid * 16];
        __syncthreads();
        const int kq = tid & 3;            // k-group (16 k's)
        const int jq = (tid >> 2) << 2;    // 4 j's
        for (int s = coll + 1; s < nsteps; ++s) {
            float pm0 = -3.0e38f, pm1 = -3.0e38f, pm2 = -3.0e38f, pm3 = -3.0e38f;
#pragma unroll
            for (int kk = 0; kk < 16; ++kk) {
                const int k = (kq << 4) + kk;
                const float uk = su[k];
                const f4 ta = *(const f4*)(sT + k * 64 + jq);
                pm0 = fmaxf(pm0, ta[0] + uk);
                pm1 = fmaxf(pm1, ta[1] + uk);
                pm2 = fmaxf(pm2, ta[2] + uk);
                pm3 = fmaxf(pm3, ta[3] + uk);
            }
            spart[(jq + 0) * 4 + kq] = pm0;
            spart[(jq + 1) * 4 + kq] = pm1;
            spart[(jq + 2) * 4 + kq] = pm2;
            spart[(jq + 3) * 4 + kq] = pm3;
            __syncthreads();                       // spart visible; su reads done
            const f4 pr = *(const f4*)(spart + tid * 4);
            const float un = sEm[s * 64 + tid] +
                fmaxf(fmaxf(pr[0], pr[1]), fmaxf(pr[2], pr[3]));
            su[tid] = un;
            __syncthreads();                       // su visible; spart reads done
        }
        const float uf = su[tid];
        float* dst = Pg + (size_t)c * 4096 + (size_t)tid * 64 + ib;
#pragma unroll
        for (int ii = 0; ii < 16; ii += 4) {
            f4 o = { uf + sv[ii], uf + sv[ii + 1], uf + sv[ii + 2], uf + sv[ii + 3] };
            *(f4*)(dst + ii) = o;
        }
        return;
    }

    // matrix-mode writeout
#pragma unroll
    for (int jj = 0; jj < 4; ++jj) {
        const f4 row = *(const f4*)(sP + (j0 + jj) * 16 + i0);
        *(f4*)(Pg + (size_t)c * 4096 + (j0 + jj) * 64 + ib + i0) = row;
    }
}

// ---------------------------------------------------------------------------
// K3: phase 2 — sequential scan, single wave, barrier-free.
// Lane j holds row j of the current chunk matrix in 16 f4 registers
// (double-buffered). Alpha is one-per-lane, broadcast via readlane.
// Alpha = fp64 base (lane-uniform) + fp32 residual (rebased each step),
// so precision matches the fp64 version to ~1e-3 while running at fp32 rate.
// No __syncthreads() -> the compiler never drains the prefetch (vmcnt(0)),
// loads of matrix c+1 overlap compute on matrix c.
// ---------------------------------------------------------------------------
__global__ __launch_bounds__(64) void k_phase2(
    const float* __restrict__ trans, const float* __restrict__ em,
    const float* __restrict__ Pg, double* __restrict__ aB)
{
    const int j = threadIdx.x;
    const double a0 = (double)trans[BOS_ID * 64 + j] + (double)em[j];
    aB[j] = a0;
    double base = __shfl(a0, 0);
    float a = (float)(a0 - base);

    f4 rP[16], rN[16];
    {
        const float* P = Pg + (size_t)j * 64;
#pragma unroll
        for (int r = 0; r < 16; ++r) rP[r] = *(const f4*)(P + 4 * r);
    }
    for (int c = 0; c < NCHUNK; ++c) {
        if (c + 1 < NCHUNK) {
            const float* Pn = Pg + (size_t)(c + 1) * 4096 + (size_t)j * 64;
#pragma unroll
            for (int r = 0; r < 16; ++r) rN[r] = *(const f4*)(Pn + 4 * r);
        }
        const unsigned au = __float_as_uint(a);
        float m0 = -3.0e38f, m1 = -3.0e38f, m2 = -3.0e38f, m3 = -3.0e38f;
#pragma unroll
        for (int i = 0; i < 64; i += 4) {
            const f4 pr = rP[i >> 2];
            m0 = fmaxf(m0, pr[0] + __uint_as_float(__builtin_amdgcn_readlane(au, i)));
            m1 = fmaxf(m1, pr[1] + __uint_as_float(__builtin_amdgcn_readlane(au, i + 1)));
            m2 = fmaxf(m2, pr[2] + __uint_as_float(__builtin_amdgcn_readlane(au, i + 2)));
            m3 = fmaxf(m3, pr[3] + __uint_as_float(__builtin_amdgcn_readlane(au, i + 3)));
        }
        const float m = fmaxf(fmaxf(m0, m1), fmaxf(m2, m3));
        const float mb = __uint_as_float(
            __builtin_amdgcn_readfirstlane(__float_as_uint(m)));
        base += (double)mb;
        a = m - mb;
        aB[(size_t)(c + 1) * 64 + j] = base + (double)a;
#pragma unroll
        for (int r = 0; r < 16; ++r) rP[r] = rN[r];
    }
}

// ---------------------------------------------------------------------------
// K4: phase 3 — per chunk, single wave, alphas in registers (readlane),
// backpointers + composed backtrack map. fp32, chunk-relative alphas.
// ---------------------------------------------------------------------------
__global__ __launch_bounds__(64) void k_phase3(
    const float* __restrict__ trans, const float* __restrict__ em,
    const double* __restrict__ aB, unsigned char* __restrict__ bp,
    unsigned char* __restrict__ gmap)
{
    __shared__ float sT[4096];            // 16 KB
    __shared__ unsigned char sbp[64 * 64];// 4 KB
    const int c = blockIdx.x;
    const int tid = threadIdx.x;          // = state j
    for (int x = tid; x < 4096; x += 64) sT[x] = trans[x];
    const double aref = aB[(size_t)c * 64];
    float a = (float)(aB[(size_t)c * 64 + tid] - aref);
    const int t0 = c * CHUNK;
    int nsteps = (T_LEN - 1) - t0; if (nsteps > CHUNK) nsteps = CHUNK;
    __syncthreads();

    for (int s = 0; s < nsteps; ++s) {
        const int t = t0 + 1 + s;
        const float e = em[(size_t)t * 64 + tid];
        float m = -3.0e38f; int bi = 0;
        const unsigned int au = __float_as_uint(a);
#pragma unroll
        for (int i = 0; i < 64; ++i) {
            const float ai = __uint_as_float(__builtin_amdgcn_readlane(au, i));
            const float v = sT[i * 64 + tid] + ai;
            if (v > m) { m = v; bi = i; }
        }
        a = e + m;
        sbp[s * 64 + tid] = (unsigned char)bi;
        bp[(size_t)t * 64 + tid] = (unsigned char)bi;
    }
    // composed map: tag at chunk end -> tag at chunk start
    int tag = tid;
    for (int r = nsteps - 1; r >= 0; --r) tag = sbp[r * 64 + tag];
    gmap[(size_t)c * 64 + tid] = (unsigned char)tag;
}

// ---------------------------------------------------------------------------
// K5: final scores + boundary tags via map composition.
// ---------------------------------------------------------------------------
__global__ __launch_bounds__(64) void k_final(
    const float* __restrict__ trans, const double* __restrict__ aB,
    const unsigned char* __restrict__ gmap, int* __restrict__ btag,
    float* __restrict__ out)
{
    __shared__ unsigned char sg[NCHUNK * 64];  // 16 KB
    __shared__ double sval[64];
    const int tid = threadIdx.x;
    for (int x = tid; x < NCHUNK * 64; x += 64) sg[x] = gmap[x];
    sval[tid] = aB[(size_t)NCHUNK * 64 + tid] + (double)trans[tid * 64 + EOS_ID];
    __syncthreads();
    if (tid == 0) {
        double bm = sval[0]; int bt = 0;
        for (int jj = 1; jj < 64; ++jj)
            if (sval[jj] > bm) { bm = sval[jj]; bt = jj; }
        out[0] = (float)bm;
        btag[NCHUNK] = bt;
        int cur = bt;
        for (int c = NCHUNK - 1; c >= 0; --c) {
            cur = sg[c * 64 + cur];
            btag[c] = cur;
        }
    }
}

// ---------------------------------------------------------------------------
// K6: per-chunk backtrack -> path written as float32.
// ---------------------------------------------------------------------------
__global__ __launch_bounds__(64) void k_path(
    const unsigned char* __restrict__ bp, const int* __restrict__ btag,
    float* __restrict__ out)
{
    __shared__ unsigned char sbp[64 * 64];
    const int c = blockIdx.x;
    const int tid = threadIdx.x;
    const int t0 = c * CHUNK;
    int nsteps = (T_LEN - 1) - t0; if (nsteps > CHUNK) nsteps = CHUNK;
    for (int r = 0; r < nsteps; ++r)
        sbp[r * 64 + tid] = bp[(size_t)(t0 + 1 + r) * 64 + tid];
    __syncthreads();
    if (tid == 0) {
        const int pe = t0 + nsteps;
        int cur = btag[c + 1];
        out[1 + pe] = (float)cur;
        for (int r = nsteps - 1; r >= 0; --r) {
            cur = sbp[r * 64 + cur];
            out[1 + t0 + r] = (float)cur;
        }
    }
}

// ---------------------------------------------------------------------------
extern "C" void kernel_launch(void* const* d_in, const int* in_sizes, int n_in,
                              void* d_out, int out_size, void* d_ws, size_t ws_size,
                              hipStream_t stream)
{
    const int*   feat = (const int*)d_in[0];
    const float* w    = (const float*)d_in[1];
    const float* tr   = (const float*)d_in[2];
    float* out = (float*)d_out;
    char*  ws  = (char*)d_ws;

    float*         em = (float*)(ws + EM_OFF);
    float*         Pg = (float*)(ws + P_OFF);
    double*        aB = (double*)(ws + AB_OFF);
    unsigned char* bp = (unsigned char*)(ws + BP_OFF);
    unsigned char* gm = (unsigned char*)(ws + G_OFF);
    int*           bt = (int*)(ws + BT_OFF);

    k_emissions<<<(T_LEN * LTAG) / 256, 256, 0, stream>>>(feat, w, em);
    k_phase1   <<<NCHUNK * 4, 64, 0, stream>>>(tr, em, Pg);
    k_phase2   <<<1,          64, 0, stream>>>(tr, em, Pg, aB);
    k_phase3   <<<NCHUNK,     64, 0, stream>>>(tr, em, aB, bp, gm);
    k_final    <<<1,          64, 0, stream>>>(tr, aB, gm, bt, out);
    k_path     <<<NCHUNK,     64, 0, stream>>>(bp, bt, out);
}

// Round 6
// 458.809 us; speedup vs baseline: 1.2581x; 1.2581x over previous
//
#include <hip/hip_runtime.h>

#define T_LEN  16384
#define LTAG   64
#define F_PER  14
#define NCHUNK 256
#define CHUNK  64
#define BOS_ID 0
#define EOS_ID 1
#define NREG   10
#define REGSZ  500000      // 10 x 500000 = 5,000,000 = NB_FEATURES ; 2 MB per region

typedef __attribute__((ext_vector_type(4))) float f4;

// workspace layout (bytes)
static constexpr size_t EM_OFF  = 0;                                   // float[T*64]  4 MB
static constexpr size_t P_OFF   = EM_OFF + (size_t)T_LEN * 64 * 4;     // float[256*4096] 4 MB
static constexpr size_t AB_OFF  = P_OFF + (size_t)NCHUNK * 4096 * 4;   // double[257*64]
static constexpr size_t BP_OFF  = AB_OFF + (size_t)257 * 64 * 8;       // uchar[T*64] 1 MB
static constexpr size_t G_OFF   = BP_OFF + (size_t)T_LEN * 64;         // uchar[256*64]
static constexpr size_t BT_OFF  = G_OFF + (size_t)NCHUNK * 64;         // int[257]
static constexpr size_t U_OFF   = BT_OFF + 4096;                       // float[256*256] u per strip
static constexpr size_t V_OFF   = U_OFF + (size_t)NCHUNK * 256 * 4;    // float[256*64]  v per strip
static constexpr size_t FLG_OFF = V_OFF + (size_t)NCHUNK * 64 * 4;     // uchar[256*4]

// ---------------------------------------------------------------------------
// K1: emissions  em[t,l] = sum_f w[feat[t,l,f]]  (fp32)
// Region-sweep gather (keeps active 2 MB table window hot in per-XCD L2).
// ---------------------------------------------------------------------------
__global__ __launch_bounds__(256) void k_emissions(
    const int* __restrict__ idx, const float* __restrict__ w, float* __restrict__ em)
{
    const int tid = blockIdx.x * 256 + threadIdx.x;
    const int* p = idx + (size_t)tid * F_PER;
    int id[F_PER];
#pragma unroll
    for (int f = 0; f < F_PER; ++f) id[f] = __builtin_nontemporal_load(p + f);
    float s = 0.f;
    for (int r = 0; r < NREG; ++r) {
        const int lo = r * REGSZ;
        const int hi = lo + REGSZ;
#pragma unroll
        for (int f = 0; f < F_PER; ++f)
            if (id[f] >= lo && id[f] < hi) s += w[id[f]];
    }
    em[tid] = s;
}

// ---------------------------------------------------------------------------
// K2: phase 1 — per-chunk (max,+) transfer matrices, fp32, column-split,
// with max-plus rank-1 collapse early-exit. Collapsed strips emit (u,v,flag=1)
// instead of the full 16-column strip of Pg; non-collapsed emit Pg + flag=0.
// ---------------------------------------------------------------------------
__global__ __launch_bounds__(64) void k_phase1(
    const float* __restrict__ trans, const float* __restrict__ em, float* __restrict__ Pg,
    float* __restrict__ U, float* __restrict__ V, unsigned char* __restrict__ flags)
{
    __shared__ float sT[4096];      // 16 KB  sT[k*64+j] = T[k][j]
    __shared__ float sP[64 * 16];   // 4 KB   sP[j*16+i] = P[j][ib+i]
    __shared__ float sEm[64 * 64];  // 16 KB  emissions for this chunk
    __shared__ float su[64];
    __shared__ float sv[16];
    __shared__ float spart[256];
    const int bb  = blockIdx.x;
    const int c   = bb >> 2;
    const int st  = bb & 3;
    const int ib  = st << 4;
    const int tid = threadIdx.x;
    const int i0  = (tid & 3) << 2;
    const int j0  = (tid >> 2) << 2;
    const int t0  = c << 6;
    int nsteps = (T_LEN - 1) - t0; if (nsteps > CHUNK) nsteps = CHUNK;
    for (int x = tid; x < 4096; x += 64) sT[x] = trans[x];
    {   // stage emissions em[t0+1 .. t0+nsteps][:] -> sEm[s*64+j]
        const float* eg = em + (size_t)(t0 + 1) * 64;
        for (int x = tid * 4; x < nsteps * 64; x += 256)
            *(f4*)(sEm + x) = *(const f4*)(eg + x);
    }
    __syncthreads();

    float acc[4][4];
    // init step s=0: P[j][i] = e0[j] + T[ib+i][j]
    {
        const f4 e = *(const f4*)(sEm + j0);
#pragma unroll
        for (int jj = 0; jj < 4; ++jj) {
#pragma unroll
            for (int ii = 0; ii < 4; ++ii)
                acc[jj][ii] = e[jj] + sT[(ib + i0 + ii) * 64 + (j0 + jj)];
            f4 row = { acc[jj][0], acc[jj][1], acc[jj][2], acc[jj][3] };
            *(f4*)(sP + (j0 + jj) * 16 + i0) = row;
        }
    }
    __syncthreads();

    int coll = -1;
    for (int s = 1; s < nsteps; ++s) {
        const f4 e = *(const f4*)(sEm + s * 64 + j0);
#pragma unroll
        for (int jj = 0; jj < 4; ++jj)
#pragma unroll
            for (int ii = 0; ii < 4; ++ii) acc[jj][ii] = -3.0e38f;
#pragma unroll 8
        for (int k = 0; k < 64; k += 2) {
            const f4 ta = *(const f4*)(sT + k * 64 + j0);
            const f4 tb = *(const f4*)(sT + (k + 1) * 64 + j0);
            const f4 pa = *(const f4*)(sP + k * 16 + i0);
            const f4 pb = *(const f4*)(sP + (k + 1) * 16 + i0);
#pragma unroll
            for (int jj = 0; jj < 4; ++jj)
#pragma unroll
                for (int ii = 0; ii < 4; ++ii)
                    acc[jj][ii] = fmaxf(fmaxf(acc[jj][ii], ta[jj] + pa[ii]),
                                        tb[jj] + pb[ii]);
        }
        __syncthreads();
#pragma unroll
        for (int jj = 0; jj < 4; ++jj) {
            f4 row = { acc[jj][0] + e[jj], acc[jj][1] + e[jj],
                       acc[jj][2] + e[jj], acc[jj][3] + e[jj] };
            *(f4*)(sP + (j0 + jj) * 16 + i0) = row;
        }
        __syncthreads();
        // rank-1 check: (P[j][i]-P[j][0]) must equal (P[0][i]-P[0][0]) for all i,j
        {
            const f4 refi = *(const f4*)(sP + i0);   // row j=0, this thread's cols
            const float ref0 = sP[0];
            float dev = 0.f;
#pragma unroll
            for (int jj = 0; jj < 4; ++jj) {
                const float cj = sP[(j0 + jj) * 16];
#pragma unroll
                for (int ii = 0; ii < 4; ++ii) {
                    const float val = acc[jj][ii] + e[jj];
                    dev = fmaxf(dev, fabsf((val - cj) - (refi[ii] - ref0)));
                }
            }
            if (__ballot(dev <= 1.0e-2f) == ~0ULL) { coll = s; break; }
        }
    }

    if (coll >= 0) {
        // P = u + v ; run cheap vector recursion on u for remaining steps
        if (tid < 16) sv[tid] = sP[tid] - sP[0];
        su[tid] = sP[tid * 16];
        __syncthreads();
        const int kq = tid & 3;            // k-group (16 k's)
        const int jq = (tid >> 2) << 2;    // 4 j's
        for (int s = coll + 1; s < nsteps; ++s) {
            float pm0 = -3.0e38f, pm1 = -3.0e38f, pm2 = -3.0e38f, pm3 = -3.0e38f;
#pragma unroll
            for (int kk = 0; kk < 16; ++kk) {
                const int k = (kq << 4) + kk;
                const float uk = su[k];
                const f4 ta = *(const f4*)(sT + k * 64 + jq);
                pm0 = fmaxf(pm0, ta[0] + uk);
                pm1 = fmaxf(pm1, ta[1] + uk);
                pm2 = fmaxf(pm2, ta[2] + uk);
                pm3 = fmaxf(pm3, ta[3] + uk);
            }
            spart[(jq + 0) * 4 + kq] = pm0;
            spart[(jq + 1) * 4 + kq] = pm1;
            spart[(jq + 2) * 4 + kq] = pm2;
            spart[(jq + 3) * 4 + kq] = pm3;
            __syncthreads();                       // spart visible; su reads done
            const f4 pr = *(const f4*)(spart + tid * 4);
            const float un = sEm[s * 64 + tid] +
                fmaxf(fmaxf(pr[0], pr[1]), fmaxf(pr[2], pr[3]));
            su[tid] = un;
            __syncthreads();                       // su visible; spart reads done
        }
        // rank-1 emit: u (64), v (16), flag=1 — no Pg write
        U[(size_t)c * 256 + tid * 4 + st] = su[tid];
        if (tid < 16) V[(size_t)c * 64 + ib + tid] = sv[tid];
        if (tid == 0) flags[c * 4 + st] = 1;
        return;
    }

    // matrix-mode writeout + flag=0
#pragma unroll
    for (int jj = 0; jj < 4; ++jj) {
        const f4 row = *(const f4*)(sP + (j0 + jj) * 16 + i0);
        *(f4*)(Pg + (size_t)c * 4096 + (j0 + jj) * 64 + ib + i0) = row;
    }
    if (tid == 0) flags[c * 4 + st] = 0;
}

// ---------------------------------------------------------------------------
// K3: phase 2 — sequential scan over rank-1 strips, single wave, barrier-free.
// Per chunk: m_s = max_{i in strip s}(v[i]+a[i]) via 16-lane segmented
// shfl_xor reduction; new_a[j] = max_s(u_s[j] + m_s). Fallback to full-row
// readlane gather for rare non-collapsed strips. fp64 base + fp32 residual.
// ---------------------------------------------------------------------------
__global__ __launch_bounds__(64) void k_phase2(
    const float* __restrict__ trans, const float* __restrict__ em,
    const float* __restrict__ Pg, const float* __restrict__ U,
    const float* __restrict__ V, const unsigned char* __restrict__ flags,
    double* __restrict__ aB)
{
    const int j = threadIdx.x;
    const double a0 = (double)trans[BOS_ID * 64 + j] + (double)em[j];
    aB[j] = a0;
    double base = __shfl(a0, 0);
    float a = (float)(a0 - base);

    for (int c = 0; c < NCHUNK; ++c) {
        const unsigned fl = *(const unsigned*)(flags + 4 * c);
        const f4 u = *(const f4*)(U + (size_t)c * 256 + j * 4);
        const float v = V[(size_t)c * 64 + j];
        // segmented 16-lane max of (v + a)
        float x = v + a;
        x = fmaxf(x, __shfl_xor(x, 1));
        x = fmaxf(x, __shfl_xor(x, 2));
        x = fmaxf(x, __shfl_xor(x, 4));
        x = fmaxf(x, __shfl_xor(x, 8));
        const unsigned xu = __float_as_uint(x);
        const float m0 = __uint_as_float(__builtin_amdgcn_readlane(xu, 0));
        const float m1 = __uint_as_float(__builtin_amdgcn_readlane(xu, 16));
        const float m2 = __uint_as_float(__builtin_amdgcn_readlane(xu, 32));
        const float m3 = __uint_as_float(__builtin_amdgcn_readlane(xu, 48));
        float best;
        if (fl == 0x01010101u) {                 // common case: all strips rank-1
            best = fmaxf(fmaxf(u[0] + m0, u[1] + m1), fmaxf(u[2] + m2, u[3] + m3));
        } else {
            const unsigned au = __float_as_uint(a);
            const float* P = Pg + (size_t)c * 4096 + (size_t)j * 64;
            best = -3.0e38f;
            if (fl & 0x000000ffu) best = fmaxf(best, u[0] + m0);
            else {
#pragma unroll
                for (int r = 0; r < 16; ++r)
                    best = fmaxf(best, P[r] +
                        __uint_as_float(__builtin_amdgcn_readlane(au, r)));
            }
            if (fl & 0x0000ff00u) best = fmaxf(best, u[1] + m1);
            else {
#pragma unroll
                for (int r = 0; r < 16; ++r)
                    best = fmaxf(best, P[16 + r] +
                        __uint_as_float(__builtin_amdgcn_readlane(au, 16 + r)));
            }
            if (fl & 0x00ff0000u) best = fmaxf(best, u[2] + m2);
            else {
#pragma unroll
                for (int r = 0; r < 16; ++r)
                    best = fmaxf(best, P[32 + r] +
                        __uint_as_float(__builtin_amdgcn_readlane(au, 32 + r)));
            }
            if (fl & 0xff000000u) best = fmaxf(best, u[3] + m3);
            else {
#pragma unroll
                for (int r = 0; r < 16; ++r)
                    best = fmaxf(best, P[48 + r] +
                        __uint_as_float(__builtin_amdgcn_readlane(au, 48 + r)));
            }
        }
        const float mb = __uint_as_float(
            __builtin_amdgcn_readfirstlane(__float_as_uint(best)));
        base += (double)mb;
        a = best - mb;
        aB[(size_t)(c + 1) * 64 + j] = base + (double)a;
    }
}

// ---------------------------------------------------------------------------
// K4: phase 3 — per chunk, single wave, alphas in registers (readlane),
// backpointers + composed backtrack map. fp32, chunk-relative alphas.
// ---------------------------------------------------------------------------
__global__ __launch_bounds__(64) void k_phase3(
    const float* __restrict__ trans, const float* __restrict__ em,
    const double* __restrict__ aB, unsigned char* __restrict__ bp,
    unsigned char* __restrict__ gmap)
{
    __shared__ float sT[4096];            // 16 KB
    __shared__ unsigned char sbp[64 * 64];// 4 KB
    const int c = blockIdx.x;
    const int tid = threadIdx.x;          // = state j
    for (int x = tid; x < 4096; x += 64) sT[x] = trans[x];
    const double aref = aB[(size_t)c * 64];
    float a = (float)(aB[(size_t)c * 64 + tid] - aref);
    const int t0 = c * CHUNK;
    int nsteps = (T_LEN - 1) - t0; if (nsteps > CHUNK) nsteps = CHUNK;
    __syncthreads();

    for (int s = 0; s < nsteps; ++s) {
        const int t = t0 + 1 + s;
        const float e = em[(size_t)t * 64 + tid];
        float m = -3.0e38f; int bi = 0;
        const unsigned int au = __float_as_uint(a);
#pragma unroll
        for (int i = 0; i < 64; ++i) {
            const float ai = __uint_as_float(__builtin_amdgcn_readlane(au, i));
            const float v = sT[i * 64 + tid] + ai;
            if (v > m) { m = v; bi = i; }
        }
        a = e + m;
        sbp[s * 64 + tid] = (unsigned char)bi;
        bp[(size_t)t * 64 + tid] = (unsigned char)bi;
    }
    // composed map: tag at chunk end -> tag at chunk start
    int tag = tid;
    for (int r = nsteps - 1; r >= 0; --r) tag = sbp[r * 64 + tag];
    gmap[(size_t)c * 64 + tid] = (unsigned char)tag;
}

// ---------------------------------------------------------------------------
// K5: final scores + boundary tags via map composition.
// ---------------------------------------------------------------------------
__global__ __launch_bounds__(64) void k_final(
    const float* __restrict__ trans, const double* __restrict__ aB,
    const unsigned char* __restrict__ gmap, int* __restrict__ btag,
    float* __restrict__ out)
{
    __shared__ unsigned char sg[NCHUNK * 64];  // 16 KB
    __shared__ double sval[64];
    const int tid = threadIdx.x;
    for (int x = tid; x < NCHUNK * 64; x += 64) sg[x] = gmap[x];
    sval[tid] = aB[(size_t)NCHUNK * 64 + tid] + (double)trans[tid * 64 + EOS_ID];
    __syncthreads();
    if (tid == 0) {
        double bm = sval[0]; int bt = 0;
        for (int jj = 1; jj < 64; ++jj)
            if (sval[jj] > bm) { bm = sval[jj]; bt = jj; }
        out[0] = (float)bm;
        btag[NCHUNK] = bt;
        int cur = bt;
        for (int c = NCHUNK - 1; c >= 0; --c) {
            cur = sg[c * 64 + cur];
            btag[c] = cur;
        }
    }
}

// ---------------------------------------------------------------------------
// K6: per-chunk backtrack -> path written as float32.
// ---------------------------------------------------------------------------
__global__ __launch_bounds__(64) void k_path(
    const unsigned char* __restrict__ bp, const int* __restrict__ btag,
    float* __restrict__ out)
{
    __shared__ unsigned char sbp[64 * 64];
    const int c = blockIdx.x;
    const int tid = threadIdx.x;
    const int t0 = c * CHUNK;
    int nsteps = (T_LEN - 1) - t0; if (nsteps > CHUNK) nsteps = CHUNK;
    for (int r = 0; r < nsteps; ++r)
        sbp[r * 64 + tid] = bp[(size_t)(t0 + 1 + r) * 64 + tid];
    __syncthreads();
    if (tid == 0) {
        const int pe = t0 + nsteps;
        int cur = btag[c + 1];
        out[1 + pe] = (float)cur;
        for (int r = nsteps - 1; r >= 0; --r) {
            cur = sbp[r * 64 + cur];
            out[1 + t0 + r] = (float)cur;
        }
    }
}

// ---------------------------------------------------------------------------
extern "C" void kernel_launch(void* const* d_in, const int* in_sizes, int n_in,
                              void* d_out, int out_size, void* d_ws, size_t ws_size,
                              hipStream_t stream)
{
    const int*   feat = (const int*)d_in[0];
    const float* w    = (const float*)d_in[1];
    const float* tr   = (const float*)d_in[2];
    float* out = (float*)d_out;
    char*  ws  = (char*)d_ws;

    float*         em = (float*)(ws + EM_OFF);
    float*         Pg = (float*)(ws + P_OFF);
    double*        aB = (double*)(ws + AB_OFF);
    unsigned char* bp = (unsigned char*)(ws + BP_OFF);
    unsigned char* gm = (unsigned char*)(ws + G_OFF);
    int*           bt = (int*)(ws + BT_OFF);
    float*         U  = (float*)(ws + U_OFF);
    float*         V  = (float*)(ws + V_OFF);
    unsigned char* fl = (unsigned char*)(ws + FLG_OFF);

    k_emissions<<<(T_LEN * LTAG) / 256, 256, 0, stream>>>(feat, w, em);
    k_phase1   <<<NCHUNK * 4, 64, 0, stream>>>(tr, em, Pg, U, V, fl);
    k_phase2   <<<1,          64, 0, stream>>>(tr, em, Pg, U, V, fl, aB);
    k_phase3   <<<NCHUNK,     64, 0, stream>>>(tr, em, aB, bp, gm);
    k_final    <<<1,          64, 0, stream>>>(tr, aB, gm, bt, out);
    k_path     <<<NCHUNK,     64, 0, stream>>>(bp, bt, out);
}